// Round 1
// baseline (259.619 us; speedup 1.0000x reference)
//
#include <hip/hip_runtime.h>

// Causal bag-of-words: out[b,t,c] = mean(x[b,0..t,c]).
// Two-pass chunked scan along T. fp32 throughout.
//
// Shapes: B=8, T=8192, C=512 (row-major B,T,C). All float32.
// Pass 1: per-(b,chunk,c4) chunk sums -> ws  (float4 ws[B][NCH][C4], 2 MiB)
// Pass 2: per-thread exclusive prefix over ws chunks, then stream chunk of x,
//         running sum, multiply by rcp(t+1), write out.

constexpr int B   = 8;
constexpr int T   = 8192;
constexpr int C   = 512;
constexpr int C4  = C / 4;    // 128 float4 per (b,t) row
constexpr int L   = 64;       // chunk length along T
constexpr int NCH = T / L;    // 128 chunks

__device__ __forceinline__ float4 f4add(float4 a, float4 b) {
    return make_float4(a.x + b.x, a.y + b.y, a.z + b.z, a.w + b.w);
}

__global__ __launch_bounds__(256) void cbow_chunksums(
        const float4* __restrict__ x, float4* __restrict__ ws) {
    const int tid   = blockIdx.x * blockDim.x + threadIdx.x; // [0, B*NCH*C4)
    const int c4    = tid & (C4 - 1);
    const int chunk = (tid / C4) & (NCH - 1);
    const int b     = tid / (C4 * NCH);

    const float4* p = x + ((b * T) + chunk * L) * C4 + c4;
    float4 s = make_float4(0.f, 0.f, 0.f, 0.f);
#pragma unroll 8
    for (int t = 0; t < L; ++t) {
        s = f4add(s, p[t * C4]);
    }
    ws[(b * NCH + chunk) * C4 + c4] = s;
}

__global__ __launch_bounds__(256) void cbow_scan(
        const float4* __restrict__ x, const float4* __restrict__ ws,
        float4* __restrict__ out) {
    const int tid   = blockIdx.x * blockDim.x + threadIdx.x;
    const int c4    = tid & (C4 - 1);
    const int chunk = (tid / C4) & (NCH - 1);
    const int b     = tid / (C4 * NCH);

    // Exclusive prefix over preceding chunk sums (ws is tiny, L2/LLC-resident).
    const float4* w = ws + b * NCH * C4 + c4;
    float4 run = make_float4(0.f, 0.f, 0.f, 0.f);
    for (int j = 0; j < chunk; ++j) {
        run = f4add(run, w[j * C4]);
    }

    const int   base = ((b * T) + chunk * L) * C4 + c4;
    const float4* p  = x + base;
    float4*       o  = out + base;
    const int     t0 = chunk * L;
#pragma unroll 4
    for (int t = 0; t < L; ++t) {
        run = f4add(run, p[t * C4]);
        const float inv = __builtin_amdgcn_rcpf((float)(t0 + t + 1));
        o[t * C4] = make_float4(run.x * inv, run.y * inv, run.z * inv, run.w * inv);
    }
}

extern "C" void kernel_launch(void* const* d_in, const int* in_sizes, int n_in,
                              void* d_out, int out_size, void* d_ws, size_t ws_size,
                              hipStream_t stream) {
    const float4* x   = (const float4*)d_in[0];
    float4*       out = (float4*)d_out;
    float4*       ws  = (float4*)d_ws;   // needs B*NCH*C4*16 = 2 MiB

    const int n_threads = B * NCH * C4;  // 131072
    const int block = 256;
    const int grid  = n_threads / block; // 512

    cbow_chunksums<<<grid, block, 0, stream>>>(x, ws);
    cbow_scan<<<grid, block, 0, stream>>>(x, ws, out);
}